// Round 7
// baseline (161.168 us; speedup 1.0000x reference)
//
#include <hip/hip_runtime.h>

// Dims fixed by setup_inputs(): B=4, C=64, H=W=64 -> T=4096, HEADS=8, dh=8, k=T/4=1024
#define T_DIM 4096
#define KD    1024
// K-scale with log2(e) folded in so attn uses native v_exp_f32 (2^x) directly
#define SCALE2 (0.35355339059327373f * 1.4426950408889634f)
#define VT_PITCH 1032
#define XS_PITCH 264   // 256 + 8 bf16 pad -> 528 B row pitch, 16B-aligned

extern "C" __device__ float __ocml_native_exp2_f32(float);   // single v_exp_f32

typedef __attribute__((ext_vector_type(8))) short bf16x8;
typedef __attribute__((ext_vector_type(4))) float f32x4;
typedef __attribute__((ext_vector_type(16))) float f32x16;

__device__ inline unsigned short f2bf(float f) {   // RNE fp32 -> bf16
  unsigned u = __float_as_uint(f);
  unsigned r = u + 0x7fffu + ((u >> 16) & 1u);
  return (unsigned short)(r >> 16);
}

__device__ inline unsigned cvt_pk_bf16(float a, float b) {  // a->lo, b->hi (RNE)
  unsigned ua = __float_as_uint(a); ua += 0x7fffu + ((ua >> 16) & 1u);
  unsigned ub = __float_as_uint(b); ub += 0x7fffu + ((ub >> 16) & 1u);
  return (ua >> 16) | (ub & 0xffff0000u);
}

__device__ inline bf16x8 mk8(unsigned a, unsigned b, unsigned c, unsigned d) {
  union { unsigned u[4]; bf16x8 v; } x;
  x.u[0] = a; x.u[1] = b; x.u[2] = c; x.u[3] = d; return x.v;
}

// ---------------------------------------------------------------------------
// K1 "front": blocks 0..511  : xe — partial[s*4+b][c][k0..k0+127]
//             (kb 8, b 4, s 16; 256-t slice). x-slice staged in LDS via
//             coalesced float2 loads (fixes R6's 64-segment/inst x-gather);
//             A-fragments then come from one ds_read_b128 each.
//             blocks 512..1023: q — Q[bh][d][t] = x @ Wq (proven body).
//   ALSO: zeroes d_out (1 float4/thread) for k_attn's atomicAdd.
// ---------------------------------------------------------------------------
__global__ __launch_bounds__(256) void k_front(const float* __restrict__ x,
                                               const float* __restrict__ E,
                                               const float* __restrict__ Wqkv,
                                               float* __restrict__ partial,
                                               float* __restrict__ Q,
                                               float* __restrict__ out) {
  __shared__ unsigned short xs[64 * XS_PITCH];   // 33 KB bf16 [c][t-local]
  const int bid = blockIdx.x;
  const int tid = threadIdx.x;

  // zero d_out: 1024 blocks * 256 thr * 16 B = 4 MB, coalesced
  ((float4*)out)[(size_t)bid * 256 + tid] = make_float4(0.f, 0.f, 0.f, 0.f);

  if (bid < 512) {
    const int kb = bid & 7;                    // 0..7 -> 128 k-cols
    const int b  = (bid >> 3) & 3;             // 0..3
    const int s  = bid >> 5;                   // 0..15 (256 t-rows each)
    const int k0 = kb * 128;
    const int lane = tid & 63;
    const int w = tid >> 6;
    const int li = lane & 15, lg = lane >> 4;

    // ---- stage x[b][c][s*256 .. +256) -> bf16 LDS, fully coalesced ----
    {
      const int tl = (tid & 127) * 2;
      const int ch = tid >> 7;                 // c parity (wave-uniform)
      const float* xb = x + ((size_t)b * 64 + ch) * T_DIM + s * 256 + tl;
#pragma unroll 8
      for (int it = 0; it < 32; ++it) {
        const int c = it * 2 + ch;
        float2 v = *(const float2*)(xb + (size_t)(it * 2) * T_DIM);
        *(unsigned*)(&xs[c * XS_PITCH + tl]) = cvt_pk_bf16(v.x, v.y);
      }
    }
    __syncthreads();

    f32x4 acc[4][2] = {};
#pragma unroll 2
    for (int tb = 0; tb < 8; ++tb) {
      const int tbase = s * 256 + tb * 32 + lg * 8;
      const int tloc  = tb * 32 + lg * 8;
      bf16x8 bq[2];
#pragma unroll
      for (int nt = 0; nt < 2; ++nt) {
        const int kcol = k0 + w * 32 + nt * 16 + li;
        float bv[8];
#pragma unroll
        for (int j = 0; j < 8; ++j)
          bv[j] = E[(size_t)(tbase + j) * KD + kcol];
        bq[nt] = mk8(cvt_pk_bf16(bv[0], bv[1]), cvt_pk_bf16(bv[2], bv[3]),
                     cvt_pk_bf16(bv[4], bv[5]), cvt_pk_bf16(bv[6], bv[7]));
      }
#pragma unroll
      for (int mt = 0; mt < 4; ++mt) {
        bf16x8 af8 = *(const bf16x8*)(&xs[(mt * 16 + li) * XS_PITCH + tloc]);
        acc[mt][0] = __builtin_amdgcn_mfma_f32_16x16x32_bf16(af8, bq[0], acc[mt][0], 0, 0, 0);
        acc[mt][1] = __builtin_amdgcn_mfma_f32_16x16x32_bf16(af8, bq[1], acc[mt][1], 0, 0, 0);
      }
    }
    float* pb = partial + ((size_t)s * 4 + b) * (64 * KD);
#pragma unroll
    for (int mt = 0; mt < 4; ++mt)
#pragma unroll
      for (int nt = 0; nt < 2; ++nt) {
        const int row = mt * 16 + lg * 4;
        const int col = k0 + w * 32 + nt * 16 + li;
#pragma unroll
        for (int reg = 0; reg < 4; ++reg)
          pb[(size_t)(row + reg) * KD + col] = acc[mt][nt][reg];
      }
  } else {
    const int idx = bid - 512;
    const int g  = idx & 7;
    const int tt = (idx >> 3) & 15;
    const int b  = idx >> 7;
    const int t  = tt * 256 + tid;
    const int col0 = g * 24;

    float acc[8];
#pragma unroll
    for (int j = 0; j < 8; ++j) acc[j] = 0.f;
    const float* xb = x + (size_t)b * 64 * T_DIM + t;
#pragma unroll 4
    for (int c = 0; c < 64; ++c) {
      float xv = xb[(size_t)c * T_DIM];               // coalesced
      const float* wr = Wqkv + c * 192 + col0;        // wave-uniform -> s_load
#pragma unroll
      for (int h = 0; h < 8; ++h) acc[h] += xv * wr[h];
    }
#pragma unroll
    for (int h = 0; h < 8; ++h)
      Q[(((size_t)(b * 8 + h)) * 8 + g) * T_DIM + t] = acc[h];
  }
}

// ---------------------------------------------------------------------------
// K2 "xkv": s-reduce (16 slices, fp32 into LDS) + K/V projection, fused.
//   R6 body with the reduce depth at 16. K stored [j][8d] for k_attn's
//   32x32 A-operand.
// ---------------------------------------------------------------------------
__global__ __launch_bounds__(256) void k_xkv(const float* __restrict__ partial,
                                             const float* __restrict__ Wqkv,
                                             uint2* __restrict__ Kg,
                                             unsigned short* __restrict__ Vg) {
  __shared__ float XPs[64 * 64];               // [c][k-local] fp32, 16 KB
  const int kb = blockIdx.x;                   // 0..15 -> k0 = kb*64
  const int h  = blockIdx.y;                   // 0..7
  const int b  = blockIdx.z;                   // 0..3
  const int tid = threadIdx.x;

  {
    const int kk = tid & 63;
    const int cg = tid >> 6;                   // 0..3
#pragma unroll 4
    for (int u = 0; u < 16; ++u) {
      const int c = cg * 16 + u;
      const size_t src = (size_t)c * KD + kb * 64 + kk;
      float a = 0.f;
#pragma unroll
      for (int s = 0; s < 16; ++s)
        a += partial[((size_t)s * 4 + b) * (64 * KD) + src];
      XPs[c * 64 + kk] = a;
    }
  }
  __syncthreads();

  const int klocal = tid & 63;
  const int sel    = (tid >> 6) & 1;           // wave-uniform: 0=K, 1=V
  const int dg     = tid >> 7;                 // wave-uniform: d-group 0/1
  const int k      = kb * 64 + klocal;

  float acc[4];
#pragma unroll
  for (int d = 0; d < 4; ++d) acc[d] = 0.f;
#pragma unroll 8
  for (int c = 0; c < 64; ++c) {
    float xv = XPs[c * 64 + klocal];                 // LDS, conflict-free
    const float* wr = Wqkv + c * 192 + (sel + 1) * 8 + h;            // s_load
#pragma unroll
    for (int d = 0; d < 4; ++d) acc[d] += xv * wr[(dg * 4 + d) * 24];
  }

  const int bh = b * 8 + h;
  if (sel == 0) {
    uint2* kg = Kg + (size_t)bh * 2048;
    // [j][8d] layout: d-halves of row k adjacent -> 16 B per j
    kg[k * 2 + dg] = make_uint2(cvt_pk_bf16(acc[0] * SCALE2, acc[1] * SCALE2),
                                cvt_pk_bf16(acc[2] * SCALE2, acc[3] * SCALE2));
  } else {
#pragma unroll
    for (int d = 0; d < 4; ++d)
      Vg[(size_t)(bh * 8 + dg * 4 + d) * KD + k] = f2bf(acc[d]);
  }
}

// ---------------------------------------------------------------------------
// K3: 32x32-MFMA flash attention + fused out-projection (R6-proven, verbatim).
// ---------------------------------------------------------------------------
__global__ __launch_bounds__(256, 4) void k_attn(const float* __restrict__ Q,
                                              const uint2* __restrict__ Kg,
                                              const unsigned short* __restrict__ Vg,
                                              const float* __restrict__ W0,
                                              float* __restrict__ out) {
  __shared__ __attribute__((aligned(16))) unsigned short Kt[1024 * 8];  // [j][8d] 16 KB
  __shared__ unsigned short Vt[9 * VT_PITCH];   // [d][j] bf16, row 8 = ones
  __shared__ float W0s[512];                    // W0[h*8+d][c], d<8, c<64
  const int bh = blockIdx.x;
  const int tid = threadIdx.x;
  const int b = bh >> 3, h = bh & 7;

  const uint4* kg4 = (const uint4*)(Kg + (size_t)bh * 2048);
  uint4* kt4 = (uint4*)Kt;
#pragma unroll
  for (int it = 0; it < 4; ++it)
    kt4[it * 256 + tid] = kg4[it * 256 + tid];
  const unsigned* vg = (const unsigned*)(Vg + (size_t)bh * 8192);
#pragma unroll
  for (int dd = 0; dd < 8; ++dd) {
#pragma unroll
    for (int it = 0; it < 2; ++it) {
      const int j2 = it * 256 + tid;
      *(unsigned*)(Vt + dd * VT_PITCH + j2 * 2) = vg[dd * 512 + j2];
    }
  }
#pragma unroll
  for (int it = 0; it < 2; ++it)
    *(unsigned*)(Vt + 8 * VT_PITCH + (it * 256 + tid) * 2) = 0x3F803F80u;  // ones
  W0s[tid]       = W0[h * 512 + tid];          // rows h*8..h*8+7, coalesced
  W0s[tid + 256] = W0[h * 512 + tid + 256];
  __syncthreads();

  const int lane = tid & 63, w = tid >> 6;
  const int icol = lane & 31, half = lane >> 5;
  const int i0w = blockIdx.y * 128 + w * 32;

  // Q fragment: B[k=d][n=i], half0 lanes hold d 0..7 for col i, half1 zero
  bf16x8 qf8 = {};
  if (lane < 32) {
    const float* qp = Q + (size_t)bh * 8 * T_DIM + i0w + icol;
    float q0 = qp[0],          q1 = qp[T_DIM],     q2 = qp[2 * T_DIM];
    float q3 = qp[3 * T_DIM],  q4 = qp[4 * T_DIM], q5 = qp[5 * T_DIM];
    float q6 = qp[6 * T_DIM],  q7 = qp[7 * T_DIM];
    qf8 = mk8(cvt_pk_bf16(q0, q1), cvt_pk_bf16(q2, q3),
              cvt_pk_bf16(q4, q5), cvt_pk_bf16(q6, q7));
  }

  f32x16 accO = {};
  for (int jt = 0; jt < 1024; jt += 32) {
    // A of S-MFMA: K[j = jt + icol][d 0..7] (half1 lanes zero)
    bf16x8 kf8 = {};
    if (lane < 32) kf8 = *(const bf16x8*)(&Kt[(jt + lane) * 8]);
    f32x16 z = {};
    f32x16 st = __builtin_amdgcn_mfma_f32_32x32x16_bf16(kf8, qf8, z, 0, 0, 0);

    unsigned e0, e1, e2, e3, e4, e5, e6, e7;
    {
      float p0  = __ocml_native_exp2_f32(st[0]),  p1  = __ocml_native_exp2_f32(st[1]);
      float p2  = __ocml_native_exp2_f32(st[2]),  p3  = __ocml_native_exp2_f32(st[3]);
      float p4  = __ocml_native_exp2_f32(st[4]),  p5  = __ocml_native_exp2_f32(st[5]);
      float p6  = __ocml_native_exp2_f32(st[6]),  p7  = __ocml_native_exp2_f32(st[7]);
      float p8  = __ocml_native_exp2_f32(st[8]),  p9  = __ocml_native_exp2_f32(st[9]);
      float p10 = __ocml_native_exp2_f32(st[10]), p11 = __ocml_native_exp2_f32(st[11]);
      float p12 = __ocml_native_exp2_f32(st[12]), p13 = __ocml_native_exp2_f32(st[13]);
      float p14 = __ocml_native_exp2_f32(st[14]), p15 = __ocml_native_exp2_f32(st[15]);
      asm("v_cvt_pk_bf16_f32 %0, %1, %2" : "=v"(e0) : "v"(p0),  "v"(p1));
      asm("v_cvt_pk_bf16_f32 %0, %1, %2" : "=v"(e1) : "v"(p2),  "v"(p3));
      asm("v_cvt_pk_bf16_f32 %0, %1, %2" : "=v"(e2) : "v"(p4),  "v"(p5));
      asm("v_cvt_pk_bf16_f32 %0, %1, %2" : "=v"(e3) : "v"(p6),  "v"(p7));
      asm("v_cvt_pk_bf16_f32 %0, %1, %2" : "=v"(e4) : "v"(p8),  "v"(p9));
      asm("v_cvt_pk_bf16_f32 %0, %1, %2" : "=v"(e5) : "v"(p10), "v"(p11));
      asm("v_cvt_pk_bf16_f32 %0, %1, %2" : "=v"(e6) : "v"(p12), "v"(p13));
      asm("v_cvt_pk_bf16_f32 %0, %1, %2" : "=v"(e7) : "v"(p14), "v"(p15));
    }
    // cross-half exchange: after these, (e0,e1,e2,e3) and (e4,e5,e6,e7) are
    // the K=16 B-fragments (P[j][i]) for PV1 (j jt..jt+15) / PV2 (jt+16..31)
    asm("v_permlane32_swap_b32 %0, %1" : "+v"(e0), "+v"(e2));
    asm("v_permlane32_swap_b32 %0, %1" : "+v"(e1), "+v"(e3));
    asm("v_permlane32_swap_b32 %0, %1" : "+v"(e4), "+v"(e6));
    asm("v_permlane32_swap_b32 %0, %1" : "+v"(e5), "+v"(e7));

    // A of PV: V''[d = icol][j], rows 9..31 zero, row 8 = ones (denominator)
    bf16x8 va0 = {}, va1 = {};
    if (icol < 9) {
      const unsigned short* vp = Vt + icol * VT_PITCH + jt + half * 8;
      va0 = *(const bf16x8*)(vp);
      va1 = *(const bf16x8*)(vp + 16);
    }
    accO = __builtin_amdgcn_mfma_f32_32x32x16_bf16(va0, mk8(e0, e1, e2, e3), accO, 0, 0, 0);
    accO = __builtin_amdgcn_mfma_f32_32x32x16_bf16(va1, mk8(e4, e5, e6, e7), accO, 0, 0, 0);
  }

  __syncthreads();                             // all jt done -> Kt LDS is dead
  float* OwW = (float*)Kt + w * 256;           // wave-private [tok 32][d 8]

  {
    float inv = 1.0f / __shfl(accO[4], icol);  // ones-row (row 8, half0 reg 4)
    float4 o = make_float4(accO[0] * inv, accO[1] * inv,
                           accO[2] * inv, accO[3] * inv);   // d = half*4 + r
    *(float4*)(OwW + icol * 8 + half * 4) = o;   // same-wave RAW ok
  }

  // out-projection: lane handles token tok, c-half ch (32 c's)
  const int tok = icol, ch = half;
  float ov[8];
#pragma unroll
  for (int d = 0; d < 8; ++d) ov[d] = OwW[tok * 8 + d];
#pragma unroll 4
  for (int j = 0; j < 32; ++j) {
    const int c = ch * 32 + j;
    float a = 0.f;
#pragma unroll
    for (int d = 0; d < 8; ++d) a += ov[d] * W0s[d * 64 + c];   // LDS broadcast
    atomicAdd(out + ((size_t)b * 64 + c) * T_DIM + i0w + tok, a);
  }
}

// ---------------------------------------------------------------------------
extern "C" void kernel_launch(void* const* d_in, const int* in_sizes, int n_in,
                              void* d_out, int out_size, void* d_ws, size_t ws_size,
                              hipStream_t stream) {
  const float* x    = (const float*)d_in[0];
  // d_in[1..4] = conv_w, conv_b, ln_g, ln_b : dead code in the reference
  const float* Wqkv = (const float*)d_in[5];
  const float* W0   = (const float*)d_in[6];
  const float* E    = (const float*)d_in[7];
  float* out = (float*)d_out;

  // workspace layout (~21 MB)
  float* Q           = (float*)d_ws;                   // 4 MB
  float* partial     = Q + 1048576;                    // 16 MB (16 s-slices)
  uint2* Kg          = (uint2*)(partial + 4194304);    // 0.5 MB
  unsigned short* Vg = (unsigned short*)(Kg + 65536);  // 0.5 MB

  k_front <<<dim3(1024),     256, 0, stream>>>(x, E, Wqkv, partial, Q, out);
  k_xkv   <<<dim3(16, 8, 4), 256, 0, stream>>>(partial, Wqkv, Kg, Vg);
  k_attn  <<<dim3(32, 32),   256, 0, stream>>>(Q, Kg, Vg, W0, out);
}

// Round 8
// 156.595 us; speedup vs baseline: 1.0292x; 1.0292x over previous
//
#include <hip/hip_runtime.h>

// Dims fixed by setup_inputs(): B=4, C=64, H=W=64 -> T=4096, HEADS=8, dh=8, k=T/4=1024
#define T_DIM 4096
#define KD    1024
// K-scale with log2(e) folded in so attn uses native v_exp_f32 (2^x) directly
#define SCALE2 (0.35355339059327373f * 1.4426950408889634f)
#define VT_PITCH 1032
#define XS_PITCH 264   // 256 + 8 bf16 pad -> 528 B row pitch, 16B-aligned
#define XP_PITCH 17    // [c][k] fp32 partial tile pitch
#define WK_PITCH 136   // 128 + 8 fp32 pad

extern "C" __device__ float __ocml_native_exp2_f32(float);   // single v_exp_f32

typedef __attribute__((ext_vector_type(8))) short bf16x8;
typedef __attribute__((ext_vector_type(4))) float f32x4;
typedef __attribute__((ext_vector_type(16))) float f32x16;

__device__ inline unsigned short f2bf(float f) {   // RNE fp32 -> bf16
  unsigned u = __float_as_uint(f);
  unsigned r = u + 0x7fffu + ((u >> 16) & 1u);
  return (unsigned short)(r >> 16);
}

__device__ inline unsigned cvt_pk_bf16(float a, float b) {  // a->lo, b->hi (RNE)
  unsigned ua = __float_as_uint(a); ua += 0x7fffu + ((ua >> 16) & 1u);
  unsigned ub = __float_as_uint(b); ub += 0x7fffu + ((ub >> 16) & 1u);
  return (ua >> 16) | (ub & 0xffff0000u);
}

__device__ inline bf16x8 mk8(unsigned a, unsigned b, unsigned c, unsigned d) {
  union { unsigned u[4]; bf16x8 v; } x;
  x.u[0] = a; x.u[1] = b; x.u[2] = c; x.u[3] = d; return x.v;
}

// ---------------------------------------------------------------------------
// K_A: blocks 0..255  : xe+kv — block (kb 64, b 4) owns 16 k-cols of
//       XP[b] = x[b]@E over the FULL t=4096 (16 chunks of 256 t staged in
//       LDS; wave w owns the w-th 32-t slice of each chunk -> per-wave
//       partial XP tiles), then reduces partials in LDS and applies the
//       K/V projection in-block: Kg ([j][8d] bf16, SCALE2) and Vg written
//       directly. Kills the partial round-trip AND the k_xkv dispatch.
//      blocks 256..511: q — Q[bh][d][t] = x @ Wq (proven body, 512-thr) +
//       zeroes d_out for k_attn's atomicAdd.
// ---------------------------------------------------------------------------
__global__ __launch_bounds__(512) void k_front(const float* __restrict__ x,
                                               const float* __restrict__ E,
                                               const float* __restrict__ Wqkv,
                                               uint2* __restrict__ Kg,
                                               unsigned short* __restrict__ Vg,
                                               float* __restrict__ Q,
                                               float* __restrict__ out) {
  // xs (bf16 x-chunk, 33.8 KB) and XPs (fp32 partials, 34.8 KB) alias:
  // xs is dead after the last chunk's MFMA (barrier-separated).
  __shared__ __attribute__((aligned(16))) float SMEM[8 * 64 * XP_PITCH]; // 34.8 KB
  __shared__ __attribute__((aligned(16))) float Wkvs[64 * WK_PITCH];     // 34.8 KB
  unsigned short* xs = (unsigned short*)SMEM;
  float* XPs = SMEM;

  const int bid = blockIdx.x;
  const int tid = threadIdx.x;

  if (bid < 256) {
    const int kb = bid >> 2;                   // 0..63 -> 16 k-cols
    const int b  = bid & 3;
    const int k0 = kb * 16;
    const int lane = tid & 63, w = tid >> 6;   // 8 waves
    const int li = lane & 15, lg = lane >> 4;

    // ---- stage Wkv slice: Wkvs[c][cg*8+d] = Wqkv[c, sel*8+h+d*24] ----
#pragma unroll
    for (int i = 0; i < 16; ++i) {
      const int idx = tid + i * 512;           // 0..8191
      const int c = idx >> 7, j = idx & 127;
      const int cg = j >> 3, d = j & 7;
      const int sel = (cg < 8) ? 1 : 2, h = cg & 7;
      Wkvs[c * WK_PITCH + j] = Wqkv[c * 192 + sel * 8 + h + d * 24];
    }

    f32x4 acc[4] = {};
    const int tl  = (tid & 127) * 2;
    const int chp = tid >> 7;                  // 0..3 (c-phase for staging)
    const int tloc = w * 32 + lg * 8;          // this wave's t-slice in chunk

    for (int ct = 0; ct < 16; ++ct) {
      // ---- stage x[b][c][ct*256 ..+256) -> bf16 LDS, fully coalesced ----
      const float* xb = x + ((size_t)b * 64 + chp) * T_DIM + ct * 256 + tl;
#pragma unroll 4
      for (int it = 0; it < 16; ++it) {
        const int c = it * 4 + chp;
        float2 v = *(const float2*)(xb + (size_t)(it * 4) * T_DIM);
        *(unsigned*)(&xs[c * XS_PITCH + tl]) = cvt_pk_bf16(v.x, v.y);
      }
      __syncthreads();

      // ---- E-fragment for this wave's 32-t slice ----
      const int tb = ct * 256 + tloc;
      float bv[8];
#pragma unroll
      for (int j = 0; j < 8; ++j)
        bv[j] = E[(size_t)(tb + j) * KD + k0 + li];
      bf16x8 bq = mk8(cvt_pk_bf16(bv[0], bv[1]), cvt_pk_bf16(bv[2], bv[3]),
                      cvt_pk_bf16(bv[4], bv[5]), cvt_pk_bf16(bv[6], bv[7]));
#pragma unroll
      for (int mt = 0; mt < 4; ++mt) {
        bf16x8 af8 = *(const bf16x8*)(&xs[(mt * 16 + li) * XS_PITCH + tloc]);
        acc[mt] = __builtin_amdgcn_mfma_f32_16x16x32_bf16(af8, bq, acc[mt], 0, 0, 0);
      }
      __syncthreads();                         // xs dead -> safe to restage
    }

    // ---- write per-wave partial XP tiles (aliases dead xs) ----
#pragma unroll
    for (int mt = 0; mt < 4; ++mt)
#pragma unroll
      for (int r = 0; r < 4; ++r)
        XPs[(w * 64 + mt * 16 + lg * 4 + r) * XP_PITCH + li] = acc[mt][r];
    __syncthreads();

    // ---- reduce 8 partials -> XPs[c][k] (wp0 slice; self-element only) ----
#pragma unroll
    for (int i = 0; i < 2; ++i) {
      const int idx = tid + i * 512;           // 0..1023 = c*16 + k
      const int c = idx >> 4, k = idx & 15;
      float s = 0.f;
#pragma unroll
      for (int wp = 0; wp < 8; ++wp) s += XPs[(wp * 64 + c) * XP_PITCH + k];
      XPs[c * XP_PITCH + k] = s;
    }
    __syncthreads();

    // ---- K/V projection epilogue: 512 thr = 16 k x 16 cg x 2 dh ----
    {
      const int k  = tid & 15;
      const int cg = (tid >> 4) & 15;          // 0..7 K(h=cg), 8..15 V(h=cg-8)
      const int dh = tid >> 8;                 // d-half 0/1
      float a4[4] = {0.f, 0.f, 0.f, 0.f};
#pragma unroll 8
      for (int c = 0; c < 64; ++c) {
        const float xv = XPs[c * XP_PITCH + k];               // broadcast
        const float4 wv = *(const float4*)(&Wkvs[c * WK_PITCH + cg * 8 + dh * 4]);
        a4[0] += xv * wv.x; a4[1] += xv * wv.y;
        a4[2] += xv * wv.z; a4[3] += xv * wv.w;
      }
      const int h = cg & 7, bh = b * 8 + h, kk2 = k0 + k;
      if (cg < 8) {
        Kg[(size_t)bh * 2048 + kk2 * 2 + dh] =
            make_uint2(cvt_pk_bf16(a4[0] * SCALE2, a4[1] * SCALE2),
                       cvt_pk_bf16(a4[2] * SCALE2, a4[3] * SCALE2));
      } else {
#pragma unroll
        for (int d = 0; d < 4; ++d)
          Vg[(size_t)(bh * 8 + dh * 4 + d) * KD + kk2] = f2bf(a4[d]);
      }
    }
  } else {
    // ---- q blocks: Q = x @ Wq (proven body, 512 threads) + out-zero ----
    const int idx = bid - 256;
    const int g  = idx & 7;                    // d-index
    const int tt = (idx >> 3) & 7;
    const int b  = idx >> 6;
    const int t  = tt * 512 + tid;
    const int col0 = g * 24;

    {  // zero d_out: 256 blocks * 512 thr * 2 float4 = 4 MB, coalesced
      float4* o4 = (float4*)out;
      o4[(size_t)idx * 1024 + tid]       = make_float4(0.f, 0.f, 0.f, 0.f);
      o4[(size_t)idx * 1024 + tid + 512] = make_float4(0.f, 0.f, 0.f, 0.f);
    }

    float acc[8];
#pragma unroll
    for (int j = 0; j < 8; ++j) acc[j] = 0.f;
    const float* xb = x + (size_t)b * 64 * T_DIM + t;
#pragma unroll 4
    for (int c = 0; c < 64; ++c) {
      float xv = xb[(size_t)c * T_DIM];               // coalesced
      const float* wr = Wqkv + c * 192 + col0;        // wave-uniform -> s_load
#pragma unroll
      for (int h = 0; h < 8; ++h) acc[h] += xv * wr[h];
    }
#pragma unroll
    for (int h = 0; h < 8; ++h)
      Q[(((size_t)(b * 8 + h)) * 8 + g) * T_DIM + t] = acc[h];
  }
}

// ---------------------------------------------------------------------------
// K_B: 32x32-MFMA flash attention + fused out-projection (R6/R7-proven body;
//      only addition: s_setprio around the MFMA clusters, T5).
// ---------------------------------------------------------------------------
__global__ __launch_bounds__(256, 4) void k_attn(const float* __restrict__ Q,
                                              const uint2* __restrict__ Kg,
                                              const unsigned short* __restrict__ Vg,
                                              const float* __restrict__ W0,
                                              float* __restrict__ out) {
  __shared__ __attribute__((aligned(16))) unsigned short Kt[1024 * 8];  // [j][8d] 16 KB
  __shared__ unsigned short Vt[9 * VT_PITCH];   // [d][j] bf16, row 8 = ones
  __shared__ float W0s[512];                    // W0[h*8+d][c], d<8, c<64
  const int bh = blockIdx.x;
  const int tid = threadIdx.x;
  const int b = bh >> 3, h = bh & 7;

  const uint4* kg4 = (const uint4*)(Kg + (size_t)bh * 2048);
  uint4* kt4 = (uint4*)Kt;
#pragma unroll
  for (int it = 0; it < 4; ++it)
    kt4[it * 256 + tid] = kg4[it * 256 + tid];
  const unsigned* vg = (const unsigned*)(Vg + (size_t)bh * 8192);
#pragma unroll
  for (int dd = 0; dd < 8; ++dd) {
#pragma unroll
    for (int it = 0; it < 2; ++it) {
      const int j2 = it * 256 + tid;
      *(unsigned*)(Vt + dd * VT_PITCH + j2 * 2) = vg[dd * 512 + j2];
    }
  }
#pragma unroll
  for (int it = 0; it < 2; ++it)
    *(unsigned*)(Vt + 8 * VT_PITCH + (it * 256 + tid) * 2) = 0x3F803F80u;  // ones
  W0s[tid]       = W0[h * 512 + tid];          // rows h*8..h*8+7, coalesced
  W0s[tid + 256] = W0[h * 512 + tid + 256];
  __syncthreads();

  const int lane = tid & 63, w = tid >> 6;
  const int icol = lane & 31, half = lane >> 5;
  const int i0w = blockIdx.y * 128 + w * 32;

  // Q fragment: B[k=d][n=i], half0 lanes hold d 0..7 for col i, half1 zero
  bf16x8 qf8 = {};
  if (lane < 32) {
    const float* qp = Q + (size_t)bh * 8 * T_DIM + i0w + icol;
    float q0 = qp[0],          q1 = qp[T_DIM],     q2 = qp[2 * T_DIM];
    float q3 = qp[3 * T_DIM],  q4 = qp[4 * T_DIM], q5 = qp[5 * T_DIM];
    float q6 = qp[6 * T_DIM],  q7 = qp[7 * T_DIM];
    qf8 = mk8(cvt_pk_bf16(q0, q1), cvt_pk_bf16(q2, q3),
              cvt_pk_bf16(q4, q5), cvt_pk_bf16(q6, q7));
  }

  f32x16 accO = {};
  for (int jt = 0; jt < 1024; jt += 32) {
    // A of S-MFMA: K[j = jt + icol][d 0..7] (half1 lanes zero)
    bf16x8 kf8 = {};
    if (lane < 32) kf8 = *(const bf16x8*)(&Kt[(jt + lane) * 8]);
    f32x16 z = {};
    __builtin_amdgcn_s_setprio(1);
    f32x16 st = __builtin_amdgcn_mfma_f32_32x32x16_bf16(kf8, qf8, z, 0, 0, 0);
    __builtin_amdgcn_s_setprio(0);

    unsigned e0, e1, e2, e3, e4, e5, e6, e7;
    {
      float p0  = __ocml_native_exp2_f32(st[0]),  p1  = __ocml_native_exp2_f32(st[1]);
      float p2  = __ocml_native_exp2_f32(st[2]),  p3  = __ocml_native_exp2_f32(st[3]);
      float p4  = __ocml_native_exp2_f32(st[4]),  p5  = __ocml_native_exp2_f32(st[5]);
      float p6  = __ocml_native_exp2_f32(st[6]),  p7  = __ocml_native_exp2_f32(st[7]);
      float p8  = __ocml_native_exp2_f32(st[8]),  p9  = __ocml_native_exp2_f32(st[9]);
      float p10 = __ocml_native_exp2_f32(st[10]), p11 = __ocml_native_exp2_f32(st[11]);
      float p12 = __ocml_native_exp2_f32(st[12]), p13 = __ocml_native_exp2_f32(st[13]);
      float p14 = __ocml_native_exp2_f32(st[14]), p15 = __ocml_native_exp2_f32(st[15]);
      asm("v_cvt_pk_bf16_f32 %0, %1, %2" : "=v"(e0) : "v"(p0),  "v"(p1));
      asm("v_cvt_pk_bf16_f32 %0, %1, %2" : "=v"(e1) : "v"(p2),  "v"(p3));
      asm("v_cvt_pk_bf16_f32 %0, %1, %2" : "=v"(e2) : "v"(p4),  "v"(p5));
      asm("v_cvt_pk_bf16_f32 %0, %1, %2" : "=v"(e3) : "v"(p6),  "v"(p7));
      asm("v_cvt_pk_bf16_f32 %0, %1, %2" : "=v"(e4) : "v"(p8),  "v"(p9));
      asm("v_cvt_pk_bf16_f32 %0, %1, %2" : "=v"(e5) : "v"(p10), "v"(p11));
      asm("v_cvt_pk_bf16_f32 %0, %1, %2" : "=v"(e6) : "v"(p12), "v"(p13));
      asm("v_cvt_pk_bf16_f32 %0, %1, %2" : "=v"(e7) : "v"(p14), "v"(p15));
    }
    // cross-half exchange: after these, (e0,e1,e2,e3) and (e4,e5,e6,e7) are
    // the K=16 B-fragments (P[j][i]) for PV1 (j jt..jt+15) / PV2 (jt+16..31)
    asm("v_permlane32_swap_b32 %0, %1" : "+v"(e0), "+v"(e2));
    asm("v_permlane32_swap_b32 %0, %1" : "+v"(e1), "+v"(e3));
    asm("v_permlane32_swap_b32 %0, %1" : "+v"(e4), "+v"(e6));
    asm("v_permlane32_swap_b32 %0, %1" : "+v"(e5), "+v"(e7));

    // A of PV: V''[d = icol][j], rows 9..31 zero, row 8 = ones (denominator)
    bf16x8 va0 = {}, va1 = {};
    if (icol < 9) {
      const unsigned short* vp = Vt + icol * VT_PITCH + jt + half * 8;
      va0 = *(const bf16x8*)(vp);
      va1 = *(const bf16x8*)(vp + 16);
    }
    __builtin_amdgcn_s_setprio(1);
    accO = __builtin_amdgcn_mfma_f32_32x32x16_bf16(va0, mk8(e0, e1, e2, e3), accO, 0, 0, 0);
    accO = __builtin_amdgcn_mfma_f32_32x32x16_bf16(va1, mk8(e4, e5, e6, e7), accO, 0, 0, 0);
    __builtin_amdgcn_s_setprio(0);
  }

  __syncthreads();                             // all jt done -> Kt LDS is dead
  float* OwW = (float*)Kt + w * 256;           // wave-private [tok 32][d 8]

  {
    float inv = 1.0f / __shfl(accO[4], icol);  // ones-row (row 8, half0 reg 4)
    float4 o = make_float4(accO[0] * inv, accO[1] * inv,
                           accO[2] * inv, accO[3] * inv);   // d = half*4 + r
    *(float4*)(OwW + icol * 8 + half * 4) = o;   // same-wave RAW ok
  }

  // out-projection: lane handles token tok, c-half ch (32 c's)
  const int tok = icol, ch = half;
  float ov[8];
#pragma unroll
  for (int d = 0; d < 8; ++d) ov[d] = OwW[tok * 8 + d];
#pragma unroll 4
  for (int j = 0; j < 32; ++j) {
    const int c = ch * 32 + j;
    float a = 0.f;
#pragma unroll
    for (int d = 0; d < 8; ++d) a += ov[d] * W0s[d * 64 + c];   // LDS broadcast
    atomicAdd(out + ((size_t)b * 64 + c) * T_DIM + i0w + tok, a);
  }
}

// ---------------------------------------------------------------------------
extern "C" void kernel_launch(void* const* d_in, const int* in_sizes, int n_in,
                              void* d_out, int out_size, void* d_ws, size_t ws_size,
                              hipStream_t stream) {
  const float* x    = (const float*)d_in[0];
  // d_in[1..4] = conv_w, conv_b, ln_g, ln_b : dead code in the reference
  const float* Wqkv = (const float*)d_in[5];
  const float* W0   = (const float*)d_in[6];
  const float* E    = (const float*)d_in[7];
  float* out = (float*)d_out;

  // workspace layout (~5 MB)
  float* Q           = (float*)d_ws;                   // 4 MB
  uint2* Kg          = (uint2*)(Q + 1048576);          // 0.5 MB
  unsigned short* Vg = (unsigned short*)(Kg + 65536);  // 0.5 MB

  k_front <<<dim3(512),    512, 0, stream>>>(x, E, Wqkv, Kg, Vg, Q, out);
  k_attn  <<<dim3(32, 32), 256, 0, stream>>>(Q, Kg, Vg, W0, out);
}

// Round 9
// 139.756 us; speedup vs baseline: 1.1532x; 1.1205x over previous
//
#include <hip/hip_runtime.h>

// Dims fixed by setup_inputs(): B=4, C=64, H=W=64 -> T=4096, HEADS=8, dh=8, k=T/4=1024
#define T_DIM 4096
#define KD    1024
// K-scale with log2(e) folded in so attn uses native v_exp_f32 (2^x) directly
#define SCALE2 (0.35355339059327373f * 1.4426950408889634f)
#define XS_PITCH 264   // 256 + 8 bf16 pad -> 528 B row pitch, 16B-aligned
#define XP_PITCH 17    // [c][k] fp32 partial tile pitch
#define WK_PITCH 136   // 128 + 8 fp32 pad
#define VC_H 648       // per-h V chunk: 9 rows x 72 bf16 pitch (2-way alias = free)

extern "C" __device__ float __ocml_native_exp2_f32(float);   // single v_exp_f32

typedef __attribute__((ext_vector_type(8))) short bf16x8;
typedef __attribute__((ext_vector_type(4))) float f32x4;
typedef __attribute__((ext_vector_type(16))) float f32x16;

__device__ inline unsigned short f2bf(float f) {   // RNE fp32 -> bf16
  unsigned u = __float_as_uint(f);
  unsigned r = u + 0x7fffu + ((u >> 16) & 1u);
  return (unsigned short)(r >> 16);
}

__device__ inline unsigned cvt_pk_bf16(float a, float b) {  // a->lo, b->hi (RNE)
  unsigned ua = __float_as_uint(a); ua += 0x7fffu + ((ua >> 16) & 1u);
  unsigned ub = __float_as_uint(b); ub += 0x7fffu + ((ub >> 16) & 1u);
  return (ua >> 16) | (ub & 0xffff0000u);
}

__device__ inline bf16x8 mk8(unsigned a, unsigned b, unsigned c, unsigned d) {
  union { unsigned u[4]; bf16x8 v; } x;
  x.u[0] = a; x.u[1] = b; x.u[2] = c; x.u[3] = d; return x.v;
}

// ---------------------------------------------------------------------------
// K_A: blocks 0..255  : xe+kv (R8-proven body). XCD-swizzled decode: the 4
//       b-copies of a kb stripe share bid%8 -> same XCD L2 -> E fetched once.
//      blocks 256..511: q (R8-proven body). out-zero REMOVED (attn no longer
//       uses atomics).
// ---------------------------------------------------------------------------
__global__ __launch_bounds__(512) void k_front(const float* __restrict__ x,
                                               const float* __restrict__ E,
                                               const float* __restrict__ Wqkv,
                                               uint2* __restrict__ Kg,
                                               unsigned short* __restrict__ Vg,
                                               float* __restrict__ Q) {
  __shared__ __attribute__((aligned(16))) float SMEM[8 * 64 * XP_PITCH]; // 34.8 KB
  __shared__ __attribute__((aligned(16))) float Wkvs[64 * WK_PITCH];     // 34.8 KB
  unsigned short* xs = (unsigned short*)SMEM;
  float* XPs = SMEM;

  const int bid = blockIdx.x;
  const int tid = threadIdx.x;

  if (bid < 256) {
    // XCD co-location: kb's 4 b-copies have identical bid%8
    const int kb = (bid & 7) + 8 * (bid >> 5);   // 0..63 -> 16 k-cols
    const int b  = (bid >> 3) & 3;
    const int k0 = kb * 16;
    const int lane = tid & 63, w = tid >> 6;     // 8 waves
    const int li = lane & 15, lg = lane >> 4;

    // ---- stage Wkv slice: Wkvs[c][cg*8+d] = Wqkv[c, sel*8+h+d*24] ----
#pragma unroll
    for (int i = 0; i < 16; ++i) {
      const int idx = tid + i * 512;           // 0..8191
      const int c = idx >> 7, j = idx & 127;
      const int cg = j >> 3, d = j & 7;
      const int sel = (cg < 8) ? 1 : 2, h = cg & 7;
      Wkvs[c * WK_PITCH + j] = Wqkv[c * 192 + sel * 8 + h + d * 24];
    }

    f32x4 acc[4] = {};
    const int tl  = (tid & 127) * 2;
    const int chp = tid >> 7;                  // 0..3 (c-phase for staging)
    const int tloc = w * 32 + lg * 8;          // this wave's t-slice in chunk

    for (int ct = 0; ct < 16; ++ct) {
      // ---- stage x[b][c][ct*256 ..+256) -> bf16 LDS, fully coalesced ----
      const float* xb = x + ((size_t)b * 64 + chp) * T_DIM + ct * 256 + tl;
#pragma unroll 4
      for (int it = 0; it < 16; ++it) {
        const int c = it * 4 + chp;
        float2 v = *(const float2*)(xb + (size_t)(it * 4) * T_DIM);
        *(unsigned*)(&xs[c * XS_PITCH + tl]) = cvt_pk_bf16(v.x, v.y);
      }
      __syncthreads();

      // ---- E-fragment for this wave's 32-t slice ----
      const int tb = ct * 256 + tloc;
      float bv[8];
#pragma unroll
      for (int j = 0; j < 8; ++j)
        bv[j] = E[(size_t)(tb + j) * KD + k0 + li];
      bf16x8 bq = mk8(cvt_pk_bf16(bv[0], bv[1]), cvt_pk_bf16(bv[2], bv[3]),
                      cvt_pk_bf16(bv[4], bv[5]), cvt_pk_bf16(bv[6], bv[7]));
#pragma unroll
      for (int mt = 0; mt < 4; ++mt) {
        bf16x8 af8 = *(const bf16x8*)(&xs[(mt * 16 + li) * XS_PITCH + tloc]);
        acc[mt] = __builtin_amdgcn_mfma_f32_16x16x32_bf16(af8, bq, acc[mt], 0, 0, 0);
      }
      __syncthreads();                         // xs dead -> safe to restage
    }

    // ---- write per-wave partial XP tiles (aliases dead xs) ----
#pragma unroll
    for (int mt = 0; mt < 4; ++mt)
#pragma unroll
      for (int r = 0; r < 4; ++r)
        XPs[(w * 64 + mt * 16 + lg * 4 + r) * XP_PITCH + li] = acc[mt][r];
    __syncthreads();

    // ---- reduce 8 partials -> XPs[c][k] ----
#pragma unroll
    for (int i = 0; i < 2; ++i) {
      const int idx = tid + i * 512;           // 0..1023 = c*16 + k
      const int c = idx >> 4, k = idx & 15;
      float s = 0.f;
#pragma unroll
      for (int wp = 0; wp < 8; ++wp) s += XPs[(wp * 64 + c) * XP_PITCH + k];
      XPs[c * XP_PITCH + k] = s;
    }
    __syncthreads();

    // ---- K/V projection epilogue: 512 thr = 16 k x 16 cg x 2 dh ----
    {
      const int k  = tid & 15;
      const int cg = (tid >> 4) & 15;          // 0..7 K(h=cg), 8..15 V(h=cg-8)
      const int dh = tid >> 8;                 // d-half 0/1
      float a4[4] = {0.f, 0.f, 0.f, 0.f};
#pragma unroll 8
      for (int c = 0; c < 64; ++c) {
        const float xv = XPs[c * XP_PITCH + k];               // broadcast
        const float4 wv = *(const float4*)(&Wkvs[c * WK_PITCH + cg * 8 + dh * 4]);
        a4[0] += xv * wv.x; a4[1] += xv * wv.y;
        a4[2] += xv * wv.z; a4[3] += xv * wv.w;
      }
      const int h = cg & 7, bh = b * 8 + h, kk2 = k0 + k;
      if (cg < 8) {
        Kg[(size_t)bh * 2048 + kk2 * 2 + dh] =
            make_uint2(cvt_pk_bf16(a4[0] * SCALE2, a4[1] * SCALE2),
                       cvt_pk_bf16(a4[2] * SCALE2, a4[3] * SCALE2));
      } else {
#pragma unroll
        for (int d = 0; d < 4; ++d)
          Vg[(size_t)(bh * 8 + dh * 4 + d) * KD + kk2] = f2bf(a4[d]);
      }
    }
  } else {
    // ---- q blocks: Q = x @ Wq (proven body, 512 threads) ----
    const int idx = bid - 256;
    const int g  = idx & 7;                    // d-index
    const int tt = (idx >> 3) & 7;
    const int b  = idx >> 6;
    const int t  = tt * 512 + tid;
    const int col0 = g * 24;

    float acc[8];
#pragma unroll
    for (int j = 0; j < 8; ++j) acc[j] = 0.f;
    const float* xb = x + (size_t)b * 64 * T_DIM + t;
#pragma unroll 4
    for (int c = 0; c < 64; ++c) {
      float xv = xb[(size_t)c * T_DIM];               // coalesced
      const float* wr = Wqkv + c * 192 + col0;        // wave-uniform -> s_load
#pragma unroll
      for (int h = 0; h < 8; ++h) acc[h] += xv * wr[h];
    }
#pragma unroll
    for (int h = 0; h < 8; ++h)
      Q[(((size_t)(b * 8 + h)) * 8 + g) * T_DIM + t] = acc[h];
  }
}

// ---------------------------------------------------------------------------
// K_B: atomic-free flash attention. Grid (iy 128, b 4) x 512 thr; wave w =
//      head h. K/V staged per-64j-chunk for ALL 8 h, double-buffered with
//      issue-early/write-late (T14). Per-wave inner math = R6/R7/R8-proven
//      32x32 path. Epilogue: block holds full 64-dim O rows for its 32
//      tokens -> W0 projection writes out DIRECTLY (no atomics, no out-zero).
// ---------------------------------------------------------------------------
__global__ __launch_bounds__(512, 4) void k_attn(const float* __restrict__ Q,
                                                 const uint2* __restrict__ Kg,
                                                 const unsigned short* __restrict__ Vg,
                                                 const float* __restrict__ W0,
                                                 float* __restrict__ out) {
  __shared__ __attribute__((aligned(16))) unsigned short Kc[2][8 * 64 * 8];  // 16 KB
  __shared__ __attribute__((aligned(16))) unsigned short Vc[2][8 * VC_H];    // 20.3 KB
  __shared__ __attribute__((aligned(16))) float W0s[64 * 64];                // 16 KB
  // Os (epilogue) aliases Kc: [32 tok][66] fp32 = 8448 B

  const int iy = blockIdx.x;                   // 0..127 -> 32 tokens
  const int b  = blockIdx.y;                   // 0..3
  const int tid = threadIdx.x;
  const int w = tid >> 6;                      // wave = head h
  const int lane = tid & 63;
  const int icol = lane & 31, half = lane >> 5;
  const int i0 = iy * 32;
  const int bh = b * 8 + w;

  // stage W0 full: [hd][c], coalesced
#pragma unroll
  for (int i = 0; i < 8; ++i) W0s[tid + i * 512] = W0[tid + i * 512];

  // ones rows (denominator) in BOTH V buffers
  {
    const int bu = tid >> 8, h = (tid >> 5) & 7, j2 = tid & 31;
    *(unsigned*)(&Vc[bu][h * VC_H + 8 * 72 + j2 * 2]) = 0x3F803F80u;
  }

  // Q fragment: B[k=d][n=i], half0 lanes hold d 0..7 for col i0+icol
  bf16x8 qf8 = {};
  if (lane < 32) {
    const float* qp = Q + (size_t)bh * 8 * T_DIM + i0 + icol;
    float q0 = qp[0],          q1 = qp[T_DIM],     q2 = qp[2 * T_DIM];
    float q3 = qp[3 * T_DIM],  q4 = qp[4 * T_DIM], q5 = qp[5 * T_DIM];
    float q6 = qp[6 * T_DIM],  q7 = qp[7 * T_DIM];
    qf8 = mk8(cvt_pk_bf16(q0, q1), cvt_pk_bf16(q2, q3),
              cvt_pk_bf16(q4, q5), cvt_pk_bf16(q6, q7));
  }

  const uint4* kg4    = (const uint4*)Kg + (size_t)b * 8192;      // [h][k] 16B
  const unsigned* vg2 = (const unsigned*)Vg + (size_t)b * 32768;  // [h][d][j2]

  // stage chunk 0 into buf 0
  {
    const int h = tid >> 6, j = tid & 63;
    *(uint4*)(&Kc[0][(h * 64 + j) * 8]) = kg4[h * 1024 + j];
#pragma unroll
    for (int i = 0; i < 4; ++i) {
      const int idx = tid + i * 512;           // 0..2047
      const int hh = idx >> 8, d = (idx >> 5) & 7, j2 = idx & 31;
      *(unsigned*)(&Vc[0][hh * VC_H + d * 72 + j2 * 2]) = vg2[(hh * 8 + d) * 512 + j2];
    }
  }
  __syncthreads();

  f32x16 accO = {};
  int buf = 0;
  for (int jc = 0; jc < 16; ++jc) {
    // T14 issue-early: next chunk's global loads before compute
    uint4 kreg = {}; unsigned vreg[4] = {};
    if (jc < 15) {
      const int h = tid >> 6, j = tid & 63;
      kreg = kg4[h * 1024 + (jc + 1) * 64 + j];
#pragma unroll
      for (int i = 0; i < 4; ++i) {
        const int idx = tid + i * 512;
        const int hh = idx >> 8, d = (idx >> 5) & 7, j2 = idx & 31;
        vreg[i] = vg2[(hh * 8 + d) * 512 + (jc + 1) * 32 + j2];
      }
    }

    // compute chunk jc (2 x 32-j sub-iterations, proven inner math)
#pragma unroll
    for (int sub = 0; sub < 2; ++sub) {
      const int jl = sub * 32;
      bf16x8 kf8 = {};
      if (lane < 32) kf8 = *(const bf16x8*)(&Kc[buf][(w * 64 + jl + lane) * 8]);
      f32x16 z = {};
      __builtin_amdgcn_s_setprio(1);
      f32x16 st = __builtin_amdgcn_mfma_f32_32x32x16_bf16(kf8, qf8, z, 0, 0, 0);
      __builtin_amdgcn_s_setprio(0);

      unsigned e0, e1, e2, e3, e4, e5, e6, e7;
      {
        float p0  = __ocml_native_exp2_f32(st[0]),  p1  = __ocml_native_exp2_f32(st[1]);
        float p2  = __ocml_native_exp2_f32(st[2]),  p3  = __ocml_native_exp2_f32(st[3]);
        float p4  = __ocml_native_exp2_f32(st[4]),  p5  = __ocml_native_exp2_f32(st[5]);
        float p6  = __ocml_native_exp2_f32(st[6]),  p7  = __ocml_native_exp2_f32(st[7]);
        float p8  = __ocml_native_exp2_f32(st[8]),  p9  = __ocml_native_exp2_f32(st[9]);
        float p10 = __ocml_native_exp2_f32(st[10]), p11 = __ocml_native_exp2_f32(st[11]);
        float p12 = __ocml_native_exp2_f32(st[12]), p13 = __ocml_native_exp2_f32(st[13]);
        float p14 = __ocml_native_exp2_f32(st[14]), p15 = __ocml_native_exp2_f32(st[15]);
        asm("v_cvt_pk_bf16_f32 %0, %1, %2" : "=v"(e0) : "v"(p0),  "v"(p1));
        asm("v_cvt_pk_bf16_f32 %0, %1, %2" : "=v"(e1) : "v"(p2),  "v"(p3));
        asm("v_cvt_pk_bf16_f32 %0, %1, %2" : "=v"(e2) : "v"(p4),  "v"(p5));
        asm("v_cvt_pk_bf16_f32 %0, %1, %2" : "=v"(e3) : "v"(p6),  "v"(p7));
        asm("v_cvt_pk_bf16_f32 %0, %1, %2" : "=v"(e4) : "v"(p8),  "v"(p9));
        asm("v_cvt_pk_bf16_f32 %0, %1, %2" : "=v"(e5) : "v"(p10), "v"(p11));
        asm("v_cvt_pk_bf16_f32 %0, %1, %2" : "=v"(e6) : "v"(p12), "v"(p13));
        asm("v_cvt_pk_bf16_f32 %0, %1, %2" : "=v"(e7) : "v"(p14), "v"(p15));
      }
      asm("v_permlane32_swap_b32 %0, %1" : "+v"(e0), "+v"(e2));
      asm("v_permlane32_swap_b32 %0, %1" : "+v"(e1), "+v"(e3));
      asm("v_permlane32_swap_b32 %0, %1" : "+v"(e4), "+v"(e6));
      asm("v_permlane32_swap_b32 %0, %1" : "+v"(e5), "+v"(e7));

      bf16x8 va0 = {}, va1 = {};
      if (icol < 9) {
        const unsigned short* vp = &Vc[buf][w * VC_H + icol * 72 + jl + half * 8];
        va0 = *(const bf16x8*)(vp);
        va1 = *(const bf16x8*)(vp + 16);
      }
      __builtin_amdgcn_s_setprio(1);
      accO = __builtin_amdgcn_mfma_f32_32x32x16_bf16(va0, mk8(e0, e1, e2, e3), accO, 0, 0, 0);
      accO = __builtin_amdgcn_mfma_f32_32x32x16_bf16(va1, mk8(e4, e5, e6, e7), accO, 0, 0, 0);
      __builtin_amdgcn_s_setprio(0);
    }

    // T14 write-late: next chunk lands after this chunk's reads
    if (jc < 15) {
      const int h = tid >> 6, j = tid & 63;
      *(uint4*)(&Kc[buf ^ 1][(h * 64 + j) * 8]) = kreg;
#pragma unroll
      for (int i = 0; i < 4; ++i) {
        const int idx = tid + i * 512;
        const int hh = idx >> 8, d = (idx >> 5) & 7, j2 = idx & 31;
        *(unsigned*)(&Vc[buf ^ 1][hh * VC_H + d * 72 + j2 * 2]) = vreg[i];
      }
    }
    __syncthreads();
    buf ^= 1;
  }

  // ---- epilogue: normalized O -> LDS (Kc dead), then direct out writes ----
  float* Os = (float*)Kc;                      // [32 tok][66] fp32
  {
    float inv = 1.0f / __shfl(accO[4], icol);  // ones-row (row 8, half0 reg 4)
    if (lane < 32 || half) {                   // all lanes write their d-half
      float4 o = make_float4(accO[0] * inv, accO[1] * inv,
                             accO[2] * inv, accO[3] * inv);  // d = half*4 + r
      *(float2*)(&Os[icol * 66 + w * 8 + half * 4])     = make_float2(o.x, o.y);
      *(float2*)(&Os[icol * 66 + w * 8 + half * 4 + 2]) = make_float2(o.z, o.w);
    }
  }
  __syncthreads();

  // out[b][c][i0+tok] = sum_hd Os[tok][hd] * W0[hd][c]
  {
    const int tok = tid & 31, cq = tid >> 5;   // cq 0..15 -> c = cq*4..+3
    float o4[4] = {0.f, 0.f, 0.f, 0.f};
#pragma unroll 8
    for (int hd = 0; hd < 64; ++hd) {
      const float ov = Os[tok * 66 + hd];                    // 2-way, free
      const float4 wv = *(const float4*)(&W0s[hd * 64 + cq * 4]);
      o4[0] += ov * wv.x; o4[1] += ov * wv.y;
      o4[2] += ov * wv.z; o4[3] += ov * wv.w;
    }
#pragma unroll
    for (int cc = 0; cc < 4; ++cc)
      out[((size_t)b * 64 + cq * 4 + cc) * T_DIM + i0 + tok] = o4[cc];
  }
}

// ---------------------------------------------------------------------------
extern "C" void kernel_launch(void* const* d_in, const int* in_sizes, int n_in,
                              void* d_out, int out_size, void* d_ws, size_t ws_size,
                              hipStream_t stream) {
  const float* x    = (const float*)d_in[0];
  // d_in[1..4] = conv_w, conv_b, ln_g, ln_b : dead code in the reference
  const float* Wqkv = (const float*)d_in[5];
  const float* W0   = (const float*)d_in[6];
  const float* E    = (const float*)d_in[7];
  float* out = (float*)d_out;

  // workspace layout (~5 MB)
  float* Q           = (float*)d_ws;                   // 4 MB
  uint2* Kg          = (uint2*)(Q + 1048576);          // 0.5 MB
  unsigned short* Vg = (unsigned short*)(Kg + 65536);  // 0.5 MB

  k_front <<<dim3(512),    512, 0, stream>>>(x, E, Wqkv, Kg, Vg, Q);
  k_attn  <<<dim3(128, 4), 512, 0, stream>>>(Q, Kg, Vg, W0, out);
}

// Round 10
// 135.730 us; speedup vs baseline: 1.1874x; 1.0297x over previous
//
#include <hip/hip_runtime.h>

// Dims fixed by setup_inputs(): B=4, C=64, H=W=64 -> T=4096, HEADS=8, dh=8, k=T/4=1024
#define T_DIM 4096
#define KD    1024
// K-scale with log2(e) folded in so attn uses native v_exp_f32 (2^x) directly
#define SCALE2 (0.35355339059327373f * 1.4426950408889634f)
#define XS_PITCH 264   // 256 + 8 bf16 pad -> 528 B row pitch, 16B-aligned
#define XP_PITCH 17    // [c][k] fp32 partial tile pitch
#define WK_PITCH 136   // 128 + 8 fp32 pad
#define VC_H 648       // per-h V chunk: 9 rows x 72 bf16 pitch (2-way alias = free)

extern "C" __device__ float __ocml_native_exp2_f32(float);   // single v_exp_f32

typedef __attribute__((ext_vector_type(8))) short bf16x8;
typedef __attribute__((ext_vector_type(4))) float f32x4;
typedef __attribute__((ext_vector_type(16))) float f32x16;

__device__ inline unsigned short f2bf(float f) {   // RNE fp32 -> bf16
  unsigned u = __float_as_uint(f);
  unsigned r = u + 0x7fffu + ((u >> 16) & 1u);
  return (unsigned short)(r >> 16);
}

__device__ inline unsigned cvt_pk_bf16(float a, float b) {  // a->lo, b->hi (RNE)
  unsigned ua = __float_as_uint(a); ua += 0x7fffu + ((ua >> 16) & 1u);
  unsigned ub = __float_as_uint(b); ub += 0x7fffu + ((ub >> 16) & 1u);
  return (ua >> 16) | (ub & 0xffff0000u);
}

__device__ inline bf16x8 mk8(unsigned a, unsigned b, unsigned c, unsigned d) {
  union { unsigned u[4]; bf16x8 v; } x;
  x.u[0] = a; x.u[1] = b; x.u[2] = c; x.u[3] = d; return x.v;
}

// ---------------------------------------------------------------------------
// K_A: blocks 0..255  : xe+kv. R9 body + T14 pipeline: x-stage double-buffered
//       (xs0/xs1 ping-pong), E prefetched one chunk ahead into regs, ONE
//       barrier per chunk. Wkv staging moved after the loop (aliases dead xs).
//       XCD-swizzled decode kept: kb's 4 b-copies share bid%8 -> E once/XCD.
//      blocks 256..511: q (proven body).
// ---------------------------------------------------------------------------
__global__ __launch_bounds__(512) void k_front(const float* __restrict__ x,
                                               const float* __restrict__ E,
                                               const float* __restrict__ Wqkv,
                                               uint2* __restrict__ Kg,
                                               unsigned short* __restrict__ Vg,
                                               float* __restrict__ Q) {
  // Region plan (68 KB): loop phase: xs0=[0,33792) xs1=[33792,67584) bf16.
  // Epilogue phase (xs dead): XPs=[0,34816) fp32, Wkvs=[34816,69632) fp32.
  __shared__ __attribute__((aligned(16))) float SMEM[17408];   // 69632 B
  unsigned short* xs0 = (unsigned short*)SMEM;
  unsigned short* xs1 = xs0 + 64 * XS_PITCH;
  float* XPs  = SMEM;
  float* Wkvs = SMEM + 8704;                   // 34816 B offset

  const int bid = blockIdx.x;
  const int tid = threadIdx.x;

  if (bid < 256) {
    // XCD co-location: kb's 4 b-copies have identical bid%8
    const int kb = (bid & 7) + 8 * (bid >> 5);   // 0..63 -> 16 k-cols
    const int b  = (bid >> 3) & 3;
    const int k0 = kb * 16;
    const int lane = tid & 63, w = tid >> 6;     // 8 waves
    const int li = lane & 15, lg = lane >> 4;

    const int tl  = (tid & 127) * 2;
    const int chp = tid >> 7;                  // 0..3 (c-phase for staging)
    const int tloc = w * 32 + lg * 8;          // this wave's t-slice in chunk

    // ---- prologue: stage chunk 0 -> xs0; pack E fragment for chunk 0 ----
    bf16x8 bq;
    {
      const float* xb = x + ((size_t)b * 64 + chp) * T_DIM + tl;
      float2 xr[16];
#pragma unroll
      for (int it = 0; it < 16; ++it)
        xr[it] = *(const float2*)(xb + (size_t)(it * 4) * T_DIM);
      float ev[8];
#pragma unroll
      for (int j = 0; j < 8; ++j)
        ev[j] = E[(size_t)(tloc + j) * KD + k0 + li];
#pragma unroll
      for (int it = 0; it < 16; ++it)
        *(unsigned*)(&xs0[(it * 4 + chp) * XS_PITCH + tl]) = cvt_pk_bf16(xr[it].x, xr[it].y);
      bq = mk8(cvt_pk_bf16(ev[0], ev[1]), cvt_pk_bf16(ev[2], ev[3]),
               cvt_pk_bf16(ev[4], ev[5]), cvt_pk_bf16(ev[6], ev[7]));
    }
    __syncthreads();

    f32x4 acc[4] = {};
    for (int ct = 0; ct < 16; ++ct) {
      unsigned short* rb = (ct & 1) ? xs1 : xs0;
      unsigned short* wb = (ct & 1) ? xs0 : xs1;

      // T14 issue-early: chunk ct+1's x and E loads go out first
      float2 xr[16]; float evn[8];
      if (ct < 15) {
        const float* xb = x + ((size_t)b * 64 + chp) * T_DIM + (ct + 1) * 256 + tl;
#pragma unroll
        for (int it = 0; it < 16; ++it)
          xr[it] = *(const float2*)(xb + (size_t)(it * 4) * T_DIM);
#pragma unroll
        for (int j = 0; j < 8; ++j)
          evn[j] = E[(size_t)((ct + 1) * 256 + tloc + j) * KD + k0 + li];
      }

      // compute chunk ct from rb (E fragment bq packed last iter)
#pragma unroll
      for (int mt = 0; mt < 4; ++mt) {
        bf16x8 af8 = *(const bf16x8*)(&rb[(mt * 16 + li) * XS_PITCH + tloc]);
        acc[mt] = __builtin_amdgcn_mfma_f32_16x16x32_bf16(af8, bq, acc[mt], 0, 0, 0);
      }

      // T14 write-late: prefetched chunk lands in the other buffer
      if (ct < 15) {
#pragma unroll
        for (int it = 0; it < 16; ++it)
          *(unsigned*)(&wb[(it * 4 + chp) * XS_PITCH + tl]) = cvt_pk_bf16(xr[it].x, xr[it].y);
        bq = mk8(cvt_pk_bf16(evn[0], evn[1]), cvt_pk_bf16(evn[2], evn[3]),
                 cvt_pk_bf16(evn[4], evn[5]), cvt_pk_bf16(evn[6], evn[7]));
      }
      __syncthreads();                         // one barrier/chunk (dbuf)
    }

    // ---- xs dead: write per-wave partial XP tiles + stage Wkv slice ----
#pragma unroll
    for (int mt = 0; mt < 4; ++mt)
#pragma unroll
      for (int r = 0; r < 4; ++r)
        XPs[(w * 64 + mt * 16 + lg * 4 + r) * XP_PITCH + li] = acc[mt][r];
#pragma unroll
    for (int i = 0; i < 16; ++i) {             // Wkvs[c][cg*8+d]
      const int idx = tid + i * 512;           // 0..8191
      const int c = idx >> 7, j = idx & 127;
      const int cg = j >> 3, d = j & 7;
      const int sel = (cg < 8) ? 1 : 2, h = cg & 7;
      Wkvs[c * WK_PITCH + j] = Wqkv[c * 192 + sel * 8 + h + d * 24];
    }
    __syncthreads();

    // ---- reduce 8 partials -> XPs[c][k] ----
#pragma unroll
    for (int i = 0; i < 2; ++i) {
      const int idx = tid + i * 512;           // 0..1023 = c*16 + k
      const int c = idx >> 4, k = idx & 15;
      float s = 0.f;
#pragma unroll
      for (int wp = 0; wp < 8; ++wp) s += XPs[(wp * 64 + c) * XP_PITCH + k];
      XPs[c * XP_PITCH + k] = s;
    }
    __syncthreads();

    // ---- K/V projection epilogue: 512 thr = 16 k x 16 cg x 2 dh ----
    {
      const int k  = tid & 15;
      const int cg = (tid >> 4) & 15;          // 0..7 K(h=cg), 8..15 V(h=cg-8)
      const int dh = tid >> 8;                 // d-half 0/1
      float a4[4] = {0.f, 0.f, 0.f, 0.f};
#pragma unroll 8
      for (int c = 0; c < 64; ++c) {
        const float xv = XPs[c * XP_PITCH + k];               // broadcast
        const float4 wv = *(const float4*)(&Wkvs[c * WK_PITCH + cg * 8 + dh * 4]);
        a4[0] += xv * wv.x; a4[1] += xv * wv.y;
        a4[2] += xv * wv.z; a4[3] += xv * wv.w;
      }
      const int h = cg & 7, bh = b * 8 + h, kk2 = k0 + k;
      if (cg < 8) {
        Kg[(size_t)bh * 2048 + kk2 * 2 + dh] =
            make_uint2(cvt_pk_bf16(a4[0] * SCALE2, a4[1] * SCALE2),
                       cvt_pk_bf16(a4[2] * SCALE2, a4[3] * SCALE2));
      } else {
#pragma unroll
        for (int d = 0; d < 4; ++d)
          Vg[(size_t)(bh * 8 + dh * 4 + d) * KD + kk2] = f2bf(a4[d]);
      }
    }
  } else {
    // ---- q blocks: Q = x @ Wq (proven body, 512 threads) ----
    const int idx = bid - 256;
    const int g  = idx & 7;                    // d-index
    const int tt = (idx >> 3) & 7;
    const int b  = idx >> 6;
    const int t  = tt * 512 + tid;
    const int col0 = g * 24;

    float acc[8];
#pragma unroll
    for (int j = 0; j < 8; ++j) acc[j] = 0.f;
    const float* xb = x + (size_t)b * 64 * T_DIM + t;
#pragma unroll 4
    for (int c = 0; c < 64; ++c) {
      float xv = xb[(size_t)c * T_DIM];               // coalesced
      const float* wr = Wqkv + c * 192 + col0;        // wave-uniform -> s_load
#pragma unroll
      for (int h = 0; h < 8; ++h) acc[h] += xv * wr[h];
    }
#pragma unroll
    for (int h = 0; h < 8; ++h)
      Q[(((size_t)(b * 8 + h)) * 8 + g) * T_DIM + t] = acc[h];
  }
}

// ---------------------------------------------------------------------------
// K_B: atomic-free flash attention (R9-proven, verbatim). Grid (iy 128, b 4)
//      x 512 thr; wave w = head h; K/V double-buffered 64-j chunks (T14);
//      direct out writes (no atomics).
// ---------------------------------------------------------------------------
__global__ __launch_bounds__(512, 4) void k_attn(const float* __restrict__ Q,
                                                 const uint2* __restrict__ Kg,
                                                 const unsigned short* __restrict__ Vg,
                                                 const float* __restrict__ W0,
                                                 float* __restrict__ out) {
  __shared__ __attribute__((aligned(16))) unsigned short Kc[2][8 * 64 * 8];  // 16 KB
  __shared__ __attribute__((aligned(16))) unsigned short Vc[2][8 * VC_H];    // 20.3 KB
  __shared__ __attribute__((aligned(16))) float W0s[64 * 64];                // 16 KB
  // Os (epilogue) aliases Kc: [32 tok][66] fp32 = 8448 B

  const int iy = blockIdx.x;                   // 0..127 -> 32 tokens
  const int b  = blockIdx.y;                   // 0..3
  const int tid = threadIdx.x;
  const int w = tid >> 6;                      // wave = head h
  const int lane = tid & 63;
  const int icol = lane & 31, half = lane >> 5;
  const int i0 = iy * 32;
  const int bh = b * 8 + w;

  // stage W0 full: [hd][c], coalesced
#pragma unroll
  for (int i = 0; i < 8; ++i) W0s[tid + i * 512] = W0[tid + i * 512];

  // ones rows (denominator) in BOTH V buffers
  {
    const int bu = tid >> 8, h = (tid >> 5) & 7, j2 = tid & 31;
    *(unsigned*)(&Vc[bu][h * VC_H + 8 * 72 + j2 * 2]) = 0x3F803F80u;
  }

  // Q fragment: B[k=d][n=i], half0 lanes hold d 0..7 for col i0+icol
  bf16x8 qf8 = {};
  if (lane < 32) {
    const float* qp = Q + (size_t)bh * 8 * T_DIM + i0 + icol;
    float q0 = qp[0],          q1 = qp[T_DIM],     q2 = qp[2 * T_DIM];
    float q3 = qp[3 * T_DIM],  q4 = qp[4 * T_DIM], q5 = qp[5 * T_DIM];
    float q6 = qp[6 * T_DIM],  q7 = qp[7 * T_DIM];
    qf8 = mk8(cvt_pk_bf16(q0, q1), cvt_pk_bf16(q2, q3),
              cvt_pk_bf16(q4, q5), cvt_pk_bf16(q6, q7));
  }

  const uint4* kg4    = (const uint4*)Kg + (size_t)b * 8192;      // [h][k] 16B
  const unsigned* vg2 = (const unsigned*)Vg + (size_t)b * 32768;  // [h][d][j2]

  // stage chunk 0 into buf 0
  {
    const int h = tid >> 6, j = tid & 63;
    *(uint4*)(&Kc[0][(h * 64 + j) * 8]) = kg4[h * 1024 + j];
#pragma unroll
    for (int i = 0; i < 4; ++i) {
      const int idx = tid + i * 512;           // 0..2047
      const int hh = idx >> 8, d = (idx >> 5) & 7, j2 = idx & 31;
      *(unsigned*)(&Vc[0][hh * VC_H + d * 72 + j2 * 2]) = vg2[(hh * 8 + d) * 512 + j2];
    }
  }
  __syncthreads();

  f32x16 accO = {};
  int buf = 0;
  for (int jc = 0; jc < 16; ++jc) {
    // T14 issue-early: next chunk's global loads before compute
    uint4 kreg = {}; unsigned vreg[4] = {};
    if (jc < 15) {
      const int h = tid >> 6, j = tid & 63;
      kreg = kg4[h * 1024 + (jc + 1) * 64 + j];
#pragma unroll
      for (int i = 0; i < 4; ++i) {
        const int idx = tid + i * 512;
        const int hh = idx >> 8, d = (idx >> 5) & 7, j2 = idx & 31;
        vreg[i] = vg2[(hh * 8 + d) * 512 + (jc + 1) * 32 + j2];
      }
    }

    // compute chunk jc (2 x 32-j sub-iterations, proven inner math)
#pragma unroll
    for (int sub = 0; sub < 2; ++sub) {
      const int jl = sub * 32;
      bf16x8 kf8 = {};
      if (lane < 32) kf8 = *(const bf16x8*)(&Kc[buf][(w * 64 + jl + lane) * 8]);
      f32x16 z = {};
      __builtin_amdgcn_s_setprio(1);
      f32x16 st = __builtin_amdgcn_mfma_f32_32x32x16_bf16(kf8, qf8, z, 0, 0, 0);
      __builtin_amdgcn_s_setprio(0);

      unsigned e0, e1, e2, e3, e4, e5, e6, e7;
      {
        float p0  = __ocml_native_exp2_f32(st[0]),  p1  = __ocml_native_exp2_f32(st[1]);
        float p2  = __ocml_native_exp2_f32(st[2]),  p3  = __ocml_native_exp2_f32(st[3]);
        float p4  = __ocml_native_exp2_f32(st[4]),  p5  = __ocml_native_exp2_f32(st[5]);
        float p6  = __ocml_native_exp2_f32(st[6]),  p7  = __ocml_native_exp2_f32(st[7]);
        float p8  = __ocml_native_exp2_f32(st[8]),  p9  = __ocml_native_exp2_f32(st[9]);
        float p10 = __ocml_native_exp2_f32(st[10]), p11 = __ocml_native_exp2_f32(st[11]);
        float p12 = __ocml_native_exp2_f32(st[12]), p13 = __ocml_native_exp2_f32(st[13]);
        float p14 = __ocml_native_exp2_f32(st[14]), p15 = __ocml_native_exp2_f32(st[15]);
        asm("v_cvt_pk_bf16_f32 %0, %1, %2" : "=v"(e0) : "v"(p0),  "v"(p1));
        asm("v_cvt_pk_bf16_f32 %0, %1, %2" : "=v"(e1) : "v"(p2),  "v"(p3));
        asm("v_cvt_pk_bf16_f32 %0, %1, %2" : "=v"(e2) : "v"(p4),  "v"(p5));
        asm("v_cvt_pk_bf16_f32 %0, %1, %2" : "=v"(e3) : "v"(p6),  "v"(p7));
        asm("v_cvt_pk_bf16_f32 %0, %1, %2" : "=v"(e4) : "v"(p8),  "v"(p9));
        asm("v_cvt_pk_bf16_f32 %0, %1, %2" : "=v"(e5) : "v"(p10), "v"(p11));
        asm("v_cvt_pk_bf16_f32 %0, %1, %2" : "=v"(e6) : "v"(p12), "v"(p13));
        asm("v_cvt_pk_bf16_f32 %0, %1, %2" : "=v"(e7) : "v"(p14), "v"(p15));
      }
      asm("v_permlane32_swap_b32 %0, %1" : "+v"(e0), "+v"(e2));
      asm("v_permlane32_swap_b32 %0, %1" : "+v"(e1), "+v"(e3));
      asm("v_permlane32_swap_b32 %0, %1" : "+v"(e4), "+v"(e6));
      asm("v_permlane32_swap_b32 %0, %1" : "+v"(e5), "+v"(e7));

      bf16x8 va0 = {}, va1 = {};
      if (icol < 9) {
        const unsigned short* vp = &Vc[buf][w * VC_H + icol * 72 + jl + half * 8];
        va0 = *(const bf16x8*)(vp);
        va1 = *(const bf16x8*)(vp + 16);
      }
      __builtin_amdgcn_s_setprio(1);
      accO = __builtin_amdgcn_mfma_f32_32x32x16_bf16(va0, mk8(e0, e1, e2, e3), accO, 0, 0, 0);
      accO = __builtin_amdgcn_mfma_f32_32x32x16_bf16(va1, mk8(e4, e5, e6, e7), accO, 0, 0, 0);
      __builtin_amdgcn_s_setprio(0);
    }

    // T14 write-late: next chunk lands after this chunk's reads
    if (jc < 15) {
      const int h = tid >> 6, j = tid & 63;
      *(uint4*)(&Kc[buf ^ 1][(h * 64 + j) * 8]) = kreg;
#pragma unroll
      for (int i = 0; i < 4; ++i) {
        const int idx = tid + i * 512;
        const int hh = idx >> 8, d = (idx >> 5) & 7, j2 = idx & 31;
        *(unsigned*)(&Vc[buf ^ 1][hh * VC_H + d * 72 + j2 * 2]) = vreg[i];
      }
    }
    __syncthreads();
    buf ^= 1;
  }

  // ---- epilogue: normalized O -> LDS (Kc dead), then direct out writes ----
  float* Os = (float*)Kc;                      // [32 tok][66] fp32
  {
    float inv = 1.0f / __shfl(accO[4], icol);  // ones-row (row 8, half0 reg 4)
    if (lane < 32 || half) {                   // all lanes write their d-half
      float4 o = make_float4(accO[0] * inv, accO[1] * inv,
                             accO[2] * inv, accO[3] * inv);  // d = half*4 + r
      *(float2*)(&Os[icol * 66 + w * 8 + half * 4])     = make_float2(o.x, o.y);
      *(float2*)(&Os[icol * 66 + w * 8 + half * 4 + 2]) = make_float2(o.z, o.w);
    }
  }
  __syncthreads();

  // out[b][c][i0+tok] = sum_hd Os[tok][hd] * W0[hd][c]
  {
    const int tok = tid & 31, cq = tid >> 5;   // cq 0..15 -> c = cq*4..+3
    float o4[4] = {0.f, 0.f, 0.f, 0.f};
#pragma unroll 8
    for (int hd = 0; hd < 64; ++hd) {
      const float ov = Os[tok * 66 + hd];                    // 2-way, free
      const float4 wv = *(const float4*)(&W0s[hd * 64 + cq * 4]);
      o4[0] += ov * wv.x; o4[1] += ov * wv.y;
      o4[2] += ov * wv.z; o4[3] += ov * wv.w;
    }
#pragma unroll
    for (int cc = 0; cc < 4; ++cc)
      out[((size_t)b * 64 + cq * 4 + cc) * T_DIM + i0 + tok] = o4[cc];
  }
}

// ---------------------------------------------------------------------------
extern "C" void kernel_launch(void* const* d_in, const int* in_sizes, int n_in,
                              void* d_out, int out_size, void* d_ws, size_t ws_size,
                              hipStream_t stream) {
  const float* x    = (const float*)d_in[0];
  // d_in[1..4] = conv_w, conv_b, ln_g, ln_b : dead code in the reference
  const float* Wqkv = (const float*)d_in[5];
  const float* W0   = (const float*)d_in[6];
  const float* E    = (const float*)d_in[7];
  float* out = (float*)d_out;

  // workspace layout (~5 MB)
  float* Q           = (float*)d_ws;                   // 4 MB
  uint2* Kg          = (uint2*)(Q + 1048576);          // 0.5 MB
  unsigned short* Vg = (unsigned short*)(Kg + 65536);  // 0.5 MB

  k_front <<<dim3(512),    512, 0, stream>>>(x, E, Wqkv, Kg, Vg, Q);
  k_attn  <<<dim3(128, 4), 512, 0, stream>>>(Q, Kg, Vg, W0, out);
}